// Round 1
// baseline (1185.601 us; speedup 1.0000x reference)
//
#include <hip/hip_runtime.h>

#define N_NODES 8192
#define N_EDGES 524288
#define KCLUST  4096

// ---------------- output layout (float elements) ----------------
// new_x          [4096,32]   @ 0          (131072)
// new_edge_index [2,524288]  @ 131072     (1048576)  all zeros
// new_edge_attr  [524288,16] @ 1179648    (8388608)  all zeros
// A              [8192,4096] @ 9568256    (33554432) all 1/4096
// new_node_types [4096,1]    @ 43122688   (4096)
// edge_mask      [524288]    @ 43126784   (524288)   all zeros
// total 43651072

// ---------------- ws layout ----------------
// [0,       1 MiB)  x_t   [8192,32] f32
// [1 MiB,   2 MiB)  agg   [8192,32] f32   (memset 0 each launch)
// [2 MiB,  +136 )   colsum[33] f32        (memset 0 each launch; [32]=node_types sum)

__global__ __launch_bounds__(256) void node_transform_k(
    const float* __restrict__ x,
    const float* __restrict__ W1, const float* __restrict__ b1,
    const float* __restrict__ W2, const float* __restrict__ b2,
    float* __restrict__ xt)
{
    int n = blockIdx.x * 256 + threadIdx.x;
    float xr[32];
    const float4* xp = (const float4*)(x + (size_t)n * 32);
    #pragma unroll
    for (int i = 0; i < 8; ++i) {
        float4 v = xp[i];
        xr[4*i+0] = v.x; xr[4*i+1] = v.y; xr[4*i+2] = v.z; xr[4*i+3] = v.w;
    }
    float hid[64];
    #pragma unroll
    for (int j = 0; j < 64; ++j) {
        float s = b1[j];
        #pragma unroll
        for (int i = 0; i < 32; ++i) s += xr[i] * W1[j*32+i];
        hid[j] = s >= 0.f ? s : 0.1f * s;   // leaky_relu 0.1
    }
    float4* op = (float4*)(xt + (size_t)n * 32);
    #pragma unroll
    for (int q = 0; q < 8; ++q) {
        float a[4];
        #pragma unroll
        for (int r = 0; r < 4; ++r) {
            int d = q*4+r;
            float s = b2[d];
            #pragma unroll
            for (int j = 0; j < 64; ++j) s += hid[j] * W2[d*64+j];
            a[r] = s;
        }
        float4 o; o.x=a[0]; o.y=a[1]; o.z=a[2]; o.w=a[3];
        op[q] = o;
    }
}

__global__ __launch_bounds__(256) void edge_k(
    const float* __restrict__ ea, const int* __restrict__ ei,
    const float* __restrict__ W1, const float* __restrict__ b1,
    const float* __restrict__ W2, const float* __restrict__ b2,
    const float* __restrict__ xt, const float* __restrict__ dsp,
    float* __restrict__ agg)
{
    int e = blockIdx.x * 256 + threadIdx.x;
    float ar[16];
    const float4* ap = (const float4*)(ea + (size_t)e * 16);
    #pragma unroll
    for (int i = 0; i < 4; ++i) {
        float4 v = ap[i];
        ar[4*i+0]=v.x; ar[4*i+1]=v.y; ar[4*i+2]=v.z; ar[4*i+3]=v.w;
    }
    float h1[32];
    #pragma unroll
    for (int j = 0; j < 32; ++j) {
        float s = b1[j];
        #pragma unroll
        for (int i = 0; i < 16; ++i) s += ar[i] * W1[j*16+i];
        h1[j] = s >= 0.f ? s : 0.1f * s;
    }
    int src = ei[e];
    int dst = ei[N_EDGES + e];
    float ds = dsp[0];
    float xs[32];
    const float4* xp = (const float4*)(xt + (size_t)src * 32);
    #pragma unroll
    for (int i = 0; i < 8; ++i) {
        float4 v = xp[i];
        xs[4*i+0]=v.x; xs[4*i+1]=v.y; xs[4*i+2]=v.z; xs[4*i+3]=v.w;
    }
    float* ag = agg + (size_t)dst * 32;
    #pragma unroll
    for (int d = 0; d < 32; ++d) {
        float s = b2[d];
        #pragma unroll
        for (int j = 0; j < 32; ++j) s += h1[j] * W2[d*32+j];
        unsafeAtomicAdd(&ag[d], xs[d] * s * ds);
    }
}

__global__ __launch_bounds__(256) void ln_colsum_k(
    const float* __restrict__ x, const float* __restrict__ agg,
    const float* __restrict__ rwp, const float* __restrict__ gamma,
    const float* __restrict__ beta, const float* __restrict__ ntypes,
    float* __restrict__ colsum)
{
    int t = threadIdx.x;
    int n = blockIdx.x * 256 + t;
    float r = rwp[0];
    float h[32];
    const float4* xp = (const float4*)(x + (size_t)n * 32);
    const float4* ap = (const float4*)(agg + (size_t)n * 32);
    float mu = 0.f;
    #pragma unroll
    for (int i = 0; i < 8; ++i) {
        float4 xv = xp[i], av = ap[i];
        h[4*i+0] = xv.x + av.x * r;
        h[4*i+1] = xv.y + av.y * r;
        h[4*i+2] = xv.z + av.z * r;
        h[4*i+3] = xv.w + av.w * r;
        mu += h[4*i+0] + h[4*i+1] + h[4*i+2] + h[4*i+3];
    }
    mu *= (1.f/32.f);
    float var = 0.f;
    #pragma unroll
    for (int d = 0; d < 32; ++d) { float dl = h[d]-mu; var += dl*dl; }
    var *= (1.f/32.f);
    float inv = 1.f / sqrtf(var + 1e-5f);

    int lane = t & 63;
    float keep = 0.f;
    #pragma unroll
    for (int d = 0; d < 32; ++d) {
        float s = (h[d]-mu) * inv * gamma[d] + beta[d];
        #pragma unroll
        for (int off = 1; off < 64; off <<= 1) s += __shfl_xor(s, off, 64);
        if (lane == d) keep = s;
    }
    float nts = ntypes[n];
    #pragma unroll
    for (int off = 1; off < 64; off <<= 1) nts += __shfl_xor(nts, off, 64);

    if (lane < 32) unsafeAtomicAdd(&colsum[lane], keep);
    if (lane == 32) unsafeAtomicAdd(&colsum[32], nts);
}

__global__ void fill_k(const float* __restrict__ colsum, float* __restrict__ out)
{
    __shared__ float s_nx[32];
    __shared__ float s_nt;
    if (threadIdx.x < 32) s_nx[threadIdx.x] = colsum[threadIdx.x] * (1.f/4096.f);
    if (threadIdx.x == 0) s_nt = colsum[32] * (1.f/4096.f);
    __syncthreads();
    const unsigned T4 = 43651072u / 4u;
    unsigned i = blockIdx.x * blockDim.x + threadIdx.x;
    unsigned stride = gridDim.x * blockDim.x;
    float4* o = (float4*)out;
    const float AV = 1.f/4096.f;   // exact
    for (unsigned v = i; v < T4; v += stride) {
        unsigned f = v * 4u;
        float4 val;
        if (f < 131072u) {                      // new_x: broadcast colsum/4096
            unsigned c = f & 31u;
            val.x = s_nx[c]; val.y = s_nx[c+1]; val.z = s_nx[c+2]; val.w = s_nx[c+3];
        } else if (f < 9568256u) {              // new_edge_index + new_edge_attr: 0
            val.x = val.y = val.z = val.w = 0.f;
        } else if (f < 43122688u) {             // A: uniform 1/4096
            val.x = val.y = val.z = val.w = AV;
        } else if (f < 43126784u) {             // new_node_types
            val.x = val.y = val.z = val.w = s_nt;
        } else {                                // edge_mask: all false
            val.x = val.y = val.z = val.w = 0.f;
        }
        o[v] = val;
    }
}

extern "C" void kernel_launch(void* const* d_in, const int* in_sizes, int n_in,
                              void* d_out, int out_size, void* d_ws, size_t ws_size,
                              hipStream_t stream) {
    const float* x     = (const float*)d_in[0];
    const int*   ei    = (const int*)  d_in[1];
    const float* ea    = (const float*)d_in[2];
    const float* ntyp  = (const float*)d_in[3];
    const float* We1   = (const float*)d_in[4];
    const float* be1   = (const float*)d_in[5];
    const float* We2   = (const float*)d_in[6];
    const float* be2   = (const float*)d_in[7];
    const float* Wn1   = (const float*)d_in[8];
    const float* bn1   = (const float*)d_in[9];
    const float* Wn2   = (const float*)d_in[10];
    const float* bn2   = (const float*)d_in[11];
    const float* rw    = (const float*)d_in[12];
    const float* dsc   = (const float*)d_in[13];
    const float* gamma = (const float*)d_in[14];
    const float* beta  = (const float*)d_in[15];

    char* ws = (char*)d_ws;
    float* xt     = (float*)(ws);
    float* agg    = (float*)(ws + (1u<<20));
    float* colsum = (float*)(ws + (2u<<20));
    float* out    = (float*)d_out;

    // zero agg (1 MiB) + colsum (33 f) in one contiguous memset
    hipMemsetAsync(agg, 0, (1u<<20) + 256, stream);

    node_transform_k<<<N_NODES/256, 256, 0, stream>>>(x, Wn1, bn1, Wn2, bn2, xt);
    edge_k<<<N_EDGES/256, 256, 0, stream>>>(ea, ei, We1, be1, We2, be2, xt, dsc, agg);
    ln_colsum_k<<<N_NODES/256, 256, 0, stream>>>(x, agg, rw, gamma, beta, ntyp, colsum);
    fill_k<<<4096, 256, 0, stream>>>(colsum, out);
}

// Round 2
// 1022.865 us; speedup vs baseline: 1.1591x; 1.1591x over previous
//
#include <hip/hip_runtime.h>

#define N_NODES 8192
#define N_EDGES 524288
#define NB 16                    // node buckets
#define NPB (N_NODES / NB)       // 512 nodes per bucket
#define LSTRIDE 33               // +1 pad: bank = (node + d) % 32 -> conflict-free
#define CH 2048                  // edges scanned per pass

// ---------------- output layout (float elements) ----------------
// new_x          [4096,32]   @ 0          (131072)
// new_edge_index [2,524288]  @ 131072     (1048576)  all zeros
// new_edge_attr  [524288,16] @ 1179648    (8388608)  all zeros
// A              [8192,4096] @ 9568256    (33554432) all 1/4096 (exact: proto rows identical)
// new_node_types [4096,1]    @ 43122688   (4096)
// edge_mask      [524288]    @ 43126784   (524288)   all zeros
// total 43651072

// ---------------- ws layout ----------------
// [0, 1 MiB)       x_t   [8192,32] f32
// [1 MiB, +256B)   colsum[33] f32   (memset 0 each launch; [32] = node_types sum)
// [2 MiB, +gb MiB) staging [NB*gb][NPB*32] f32  (fully written, no init needed)

__global__ __launch_bounds__(256) void node_transform_k(
    const float* __restrict__ x,
    const float* __restrict__ W1, const float* __restrict__ b1,
    const float* __restrict__ W2, const float* __restrict__ b2,
    float* __restrict__ xt)
{
    int n = blockIdx.x * 256 + threadIdx.x;
    float xr[32];
    const float4* xp = (const float4*)(x + (size_t)n * 32);
    #pragma unroll
    for (int i = 0; i < 8; ++i) {
        float4 v = xp[i];
        xr[4*i+0] = v.x; xr[4*i+1] = v.y; xr[4*i+2] = v.z; xr[4*i+3] = v.w;
    }
    float hid[64];
    #pragma unroll
    for (int j = 0; j < 64; ++j) {
        float s = b1[j];
        #pragma unroll
        for (int i = 0; i < 32; ++i) s += xr[i] * W1[j*32+i];
        hid[j] = s >= 0.f ? s : 0.1f * s;   // leaky_relu 0.1
    }
    float4* op = (float4*)(xt + (size_t)n * 32);
    #pragma unroll
    for (int q = 0; q < 8; ++q) {
        float a[4];
        #pragma unroll
        for (int r = 0; r < 4; ++r) {
            int d = q*4+r;
            float s = b2[d];
            #pragma unroll
            for (int j = 0; j < 64; ++j) s += hid[j] * W2[d*64+j];
            a[r] = s;
        }
        float4 o; o.x=a[0]; o.y=a[1]; o.z=a[2]; o.w=a[3];
        op[q] = o;
    }
}

// One block = (edge-range slice g, node bucket b). Scans its slice's dst,
// ballot-compacts matching edges into an LDS queue, densely runs the edge MLP
// + x_t gather, accumulates into a padded LDS tile with ds_add_f32, then
// flushes NON-atomically to its private staging slot.
__global__ __launch_bounds__(256) void bucket_k(
    const float* __restrict__ ea, const int* __restrict__ ei,
    const float* __restrict__ W1, const float* __restrict__ b1,
    const float* __restrict__ W2, const float* __restrict__ b2,
    const float* __restrict__ xt, const float* __restrict__ dsp,
    float* __restrict__ staging, int gb, int epb)
{
    __shared__ float lagg[NPB * LSTRIDE];   // 67.6 KB
    __shared__ unsigned queue[CH];          // 8 KB (worst case: whole pass matches)
    __shared__ unsigned qcount;

    int t = threadIdx.x;
    int g = blockIdx.x;        // edge-range slice
    int b = blockIdx.y;        // node bucket

    for (int i = t; i < NPB * LSTRIDE; i += 256) lagg[i] = 0.f;
    float ds = dsp[0];
    int ebase = g * epb;
    int lane = t & 63;
    int passes = epb / CH;

    for (int pass = 0; pass < passes; ++pass) {
        if (t == 0) qcount = 0;
        __syncthreads();
        // ---- scan + compact ----
        #pragma unroll
        for (int i = 0; i < CH / 256; ++i) {
            int loff = pass * CH + i * 256 + t;            // coalesced
            int dst = ei[N_EDGES + ebase + loff];
            bool mine = ((dst >> 9) == b);
            unsigned long long m = __ballot(mine);
            unsigned base = 0;
            if (lane == 0 && m) base = atomicAdd(&qcount, (unsigned)__popcll(m));
            base = (unsigned)__shfl((int)base, 0, 64);
            if (mine) {
                unsigned pos = base + (unsigned)__popcll(m & ((1ull << lane) - 1ull));
                queue[pos] = ((unsigned)loff << 9) | (unsigned)(dst & (NPB - 1));
            }
        }
        __syncthreads();
        unsigned qn = qcount;
        // ---- dense edge MLP + LDS accumulate ----
        for (unsigned qi = t; qi < qn; qi += 256) {
            unsigned pk = queue[qi];
            int loff = (int)(pk >> 9);
            int node = (int)(pk & (NPB - 1));
            int e = ebase + loff;
            int src = ei[e];
            const float4* xp = (const float4*)(xt + (size_t)src * 32);
            float xs[32];
            #pragma unroll
            for (int i = 0; i < 8; ++i) {
                float4 v = xp[i];
                xs[4*i+0]=v.x; xs[4*i+1]=v.y; xs[4*i+2]=v.z; xs[4*i+3]=v.w;
            }
            const float4* ap = (const float4*)(ea + (size_t)e * 16);
            float ar[16];
            #pragma unroll
            for (int i = 0; i < 4; ++i) {
                float4 v = ap[i];
                ar[4*i+0]=v.x; ar[4*i+1]=v.y; ar[4*i+2]=v.z; ar[4*i+3]=v.w;
            }
            float h1[32];
            #pragma unroll
            for (int j = 0; j < 32; ++j) {
                float s = b1[j];
                #pragma unroll
                for (int i = 0; i < 16; ++i) s += ar[i] * W1[j*16+i];
                h1[j] = s >= 0.f ? s : 0.1f * s;
            }
            int lb = node * LSTRIDE;
            #pragma unroll
            for (int d = 0; d < 32; ++d) {
                float s = b2[d];
                #pragma unroll
                for (int j = 0; j < 32; ++j) s += h1[j] * W2[d*32+j];
                atomicAdd(&lagg[lb + d], xs[d] * s * ds);   // ds_add_f32, bank-spread
            }
        }
        __syncthreads();
    }
    // ---- non-atomic flush to private staging slot ----
    const size_t sbase = (size_t)(b * gb + g) * (NPB * 32);
    for (int i = t; i < NPB * 32; i += 256) {
        staging[sbase + i] = lagg[(i >> 5) * LSTRIDE + (i & 31)];
    }
}

__global__ __launch_bounds__(256) void ln_colsum_k(
    const float* __restrict__ x, const float* __restrict__ staging,
    const float* __restrict__ rwp, const float* __restrict__ gamma,
    const float* __restrict__ beta, const float* __restrict__ ntypes,
    float* __restrict__ colsum, int gb)
{
    int t = threadIdx.x;
    int n = blockIdx.x * 256 + t;
    int b = n >> 9;              // bucket
    int nn = n & (NPB - 1);
    float acc[32];
    #pragma unroll
    for (int d = 0; d < 32; ++d) acc[d] = 0.f;
    for (int g = 0; g < gb; ++g) {   // fold the staging reduce (coalesced)
        const float4* sp = (const float4*)(staging
            + (size_t)(b * gb + g) * (NPB * 32) + (size_t)nn * 32);
        #pragma unroll
        for (int i = 0; i < 8; ++i) {
            float4 v = sp[i];
            acc[4*i+0]+=v.x; acc[4*i+1]+=v.y; acc[4*i+2]+=v.z; acc[4*i+3]+=v.w;
        }
    }
    float r = rwp[0];
    const float4* xp = (const float4*)(x + (size_t)n * 32);
    float h[32];
    float mu = 0.f;
    #pragma unroll
    for (int i = 0; i < 8; ++i) {
        float4 xv = xp[i];
        h[4*i+0] = xv.x + acc[4*i+0] * r;
        h[4*i+1] = xv.y + acc[4*i+1] * r;
        h[4*i+2] = xv.z + acc[4*i+2] * r;
        h[4*i+3] = xv.w + acc[4*i+3] * r;
        mu += h[4*i+0] + h[4*i+1] + h[4*i+2] + h[4*i+3];
    }
    mu *= (1.f/32.f);
    float var = 0.f;
    #pragma unroll
    for (int d = 0; d < 32; ++d) { float dl = h[d]-mu; var += dl*dl; }
    var *= (1.f/32.f);
    float inv = 1.f / sqrtf(var + 1e-5f);

    int lane = t & 63;
    float keep = 0.f;
    #pragma unroll
    for (int d = 0; d < 32; ++d) {
        float s = (h[d]-mu) * inv * gamma[d] + beta[d];
        #pragma unroll
        for (int off = 1; off < 64; off <<= 1) s += __shfl_xor(s, off, 64);
        if (lane == d) keep = s;
    }
    float nts = ntypes[n];
    #pragma unroll
    for (int off = 1; off < 64; off <<= 1) nts += __shfl_xor(nts, off, 64);

    if (lane < 32) unsafeAtomicAdd(&colsum[lane], keep);
    if (lane == 32) unsafeAtomicAdd(&colsum[32], nts);
}

__global__ void fill_k(const float* __restrict__ colsum, float* __restrict__ out)
{
    __shared__ float s_nx[32];
    __shared__ float s_nt;
    if (threadIdx.x < 32) s_nx[threadIdx.x] = colsum[threadIdx.x] * (1.f/4096.f);
    if (threadIdx.x == 0) s_nt = colsum[32] * (1.f/4096.f);
    __syncthreads();
    const unsigned T4 = 43651072u / 4u;
    unsigned i = blockIdx.x * blockDim.x + threadIdx.x;
    unsigned stride = gridDim.x * blockDim.x;
    float4* o = (float4*)out;
    const float AV = 1.f/4096.f;   // exact: softmax of k identical logits
    for (unsigned v = i; v < T4; v += stride) {
        unsigned f = v * 4u;
        float4 val;
        if (f < 131072u) {                      // new_x: colsum(h)/4096 broadcast
            unsigned c = f & 31u;
            val.x = s_nx[c]; val.y = s_nx[c+1]; val.z = s_nx[c+2]; val.w = s_nx[c+3];
        } else if (f < 9568256u) {              // new_edge_index + new_edge_attr: 0
            val.x = val.y = val.z = val.w = 0.f;
        } else if (f < 43122688u) {             // A: uniform 1/4096
            val.x = val.y = val.z = val.w = AV;
        } else if (f < 43126784u) {             // new_node_types
            val.x = val.y = val.z = val.w = s_nt;
        } else {                                // edge_mask: all false
            val.x = val.y = val.z = val.w = 0.f;
        }
        o[v] = val;
    }
}

extern "C" void kernel_launch(void* const* d_in, const int* in_sizes, int n_in,
                              void* d_out, int out_size, void* d_ws, size_t ws_size,
                              hipStream_t stream) {
    const float* x     = (const float*)d_in[0];
    const int*   ei    = (const int*)  d_in[1];
    const float* ea    = (const float*)d_in[2];
    const float* ntyp  = (const float*)d_in[3];
    const float* We1   = (const float*)d_in[4];
    const float* be1   = (const float*)d_in[5];
    const float* We2   = (const float*)d_in[6];
    const float* be2   = (const float*)d_in[7];
    const float* Wn1   = (const float*)d_in[8];
    const float* bn1   = (const float*)d_in[9];
    const float* Wn2   = (const float*)d_in[10];
    const float* bn2   = (const float*)d_in[11];
    const float* rw    = (const float*)d_in[12];
    const float* dsc   = (const float*)d_in[13];
    const float* gamma = (const float*)d_in[14];
    const float* beta  = (const float*)d_in[15];

    char* ws = (char*)d_ws;
    float* xt      = (float*)(ws);
    float* colsum  = (float*)(ws + (1u<<20));
    float* staging = (float*)(ws + (2u<<20));
    float* out     = (float*)d_out;

    // adaptive slice count: staging needs gb MiB beyond the first 2 MiB
    int gb = 32;
    while (gb > 1 && (size_t)(2u<<20) + (size_t)gb * (1u<<20) > ws_size) gb >>= 1;
    int epb = N_EDGES / gb;

    hipMemsetAsync(colsum, 0, 256, stream);

    node_transform_k<<<N_NODES/256, 256, 0, stream>>>(x, Wn1, bn1, Wn2, bn2, xt);
    bucket_k<<<dim3(gb, NB), 256, 0, stream>>>(ea, ei, We1, be1, We2, be2, xt, dsc,
                                               staging, gb, epb);
    ln_colsum_k<<<N_NODES/256, 256, 0, stream>>>(x, staging, rw, gamma, beta, ntyp,
                                                 colsum, gb);
    fill_k<<<4096, 256, 0, stream>>>(colsum, out);
}

// Round 4
// 494.177 us; speedup vs baseline: 2.3991x; 2.0698x over previous
//
#include <hip/hip_runtime.h>

#define N_NODES 8192
#define N_EDGES 524288
#define NB 16                    // node buckets
#define NPB (N_NODES / NB)       // 512 nodes per bucket
#define LSTRIDE 33               // +1 pad: bank = (node + d) % 32 -> conflict-free
#define CH 2048                  // edges scanned per pass

// ---------------- output layout (float elements) ----------------
// new_x          [4096,32]   @ 0          (131072)
// new_edge_index [2,524288]  @ 131072     (1048576)  all zeros
// new_edge_attr  [524288,16] @ 1179648    (8388608)  all zeros
// A              [8192,4096] @ 9568256    (33554432) all 1/4096 (exact: proto rows identical)
// new_node_types [4096,1]    @ 43122688   (4096)
// edge_mask      [524288]    @ 43126784   (524288)   all zeros
// total 43651072

// ---------------- ws layout ----------------
// [0, 1 MiB)        x_t   [8192,32] f32
// [1 MiB, +256B)    colsum[33] f32   (memset 0 each launch; [32] = node_types sum)
// [2 MiB, 34 MiB)   msg   [E][16] u32 (packed 2x bf16)  -- includes xs*te*ds
// [34 MiB, +gb MiB) staging [NB*gb][NPB*32] f32 (fully written, no init)

__device__ __forceinline__ unsigned bf16rn(float f) {
    unsigned u = __float_as_uint(f);
    return (u + 0x7fffu + ((u >> 16) & 1u)) >> 16;   // round-to-nearest-even
}

__global__ __launch_bounds__(256) void node_transform_k(
    const float* __restrict__ x,
    const float* __restrict__ W1, const float* __restrict__ b1,
    const float* __restrict__ W2, const float* __restrict__ b2,
    float* __restrict__ xt)
{
    __shared__ float sW1[64*32], sW2[32*64], sb1[64], sb2[32];
    int t = threadIdx.x;
    for (int i = t; i < 2048; i += 256) { sW1[i] = W1[i]; sW2[i] = W2[i]; }
    if (t < 64) sb1[t] = b1[t];
    if (t < 32) sb2[t] = b2[t];
    __syncthreads();

    int n = blockIdx.x * 256 + t;
    float xr[32];
    const float4* xp = (const float4*)(x + (size_t)n * 32);
    #pragma unroll
    for (int i = 0; i < 8; ++i) {
        float4 v = xp[i];
        xr[4*i+0] = v.x; xr[4*i+1] = v.y; xr[4*i+2] = v.z; xr[4*i+3] = v.w;
    }
    float hid[64];
    #pragma unroll
    for (int j = 0; j < 64; ++j) {
        float s = sb1[j];
        #pragma unroll
        for (int i = 0; i < 32; ++i) s += xr[i] * sW1[j*32+i];
        hid[j] = s >= 0.f ? s : 0.1f * s;   // leaky_relu 0.1
    }
    float4* op = (float4*)(xt + (size_t)n * 32);
    #pragma unroll
    for (int q = 0; q < 8; ++q) {
        float a[4];
        #pragma unroll
        for (int r = 0; r < 4; ++r) {
            int d = q*4+r;
            float s = sb2[d];
            #pragma unroll
            for (int j = 0; j < 64; ++j) s += hid[j] * sW2[d*64+j];
            a[r] = s;
        }
        float4 o; o.x=a[0]; o.y=a[1]; o.z=a[2]; o.w=a[3];
        op[q] = o;
    }
}

// One thread per edge: edge MLP (weights in LDS) * gathered x_t[src] * ds,
// packed to bf16 and stored coalesced. No atomics.
__global__ __launch_bounds__(256) void edge_msg_k(
    const float* __restrict__ ea, const int* __restrict__ ei,
    const float* __restrict__ W1, const float* __restrict__ b1,
    const float* __restrict__ W2, const float* __restrict__ b2,
    const float* __restrict__ xt, const float* __restrict__ dsp,
    unsigned* __restrict__ msg)
{
    __shared__ float sW1[32*16], sW2[32*32], sb1[32], sb2[32];
    int t = threadIdx.x;
    for (int i = t; i < 512; i += 256)  sW1[i] = W1[i];
    for (int i = t; i < 1024; i += 256) sW2[i] = W2[i];
    if (t < 32) { sb1[t] = b1[t]; sb2[t] = b2[t]; }
    __syncthreads();

    int e = blockIdx.x * 256 + t;
    float ar[16];
    const float4* ap = (const float4*)(ea + (size_t)e * 16);
    #pragma unroll
    for (int i = 0; i < 4; ++i) {
        float4 v = ap[i];
        ar[4*i+0]=v.x; ar[4*i+1]=v.y; ar[4*i+2]=v.z; ar[4*i+3]=v.w;
    }
    int src = ei[e];
    const float4* xp = (const float4*)(xt + (size_t)src * 32);
    float xs[32];
    #pragma unroll
    for (int i = 0; i < 8; ++i) {
        float4 v = xp[i];
        xs[4*i+0]=v.x; xs[4*i+1]=v.y; xs[4*i+2]=v.z; xs[4*i+3]=v.w;
    }
    float h1[32];
    #pragma unroll
    for (int j = 0; j < 32; ++j) {
        float s = sb1[j];
        #pragma unroll
        for (int i = 0; i < 16; ++i) s += ar[i] * sW1[j*16+i];
        h1[j] = s >= 0.f ? s : 0.1f * s;
    }
    float ds = dsp[0];
    unsigned ob[16];
    #pragma unroll
    for (int dd = 0; dd < 16; ++dd) {
        float m2[2];
        #pragma unroll
        for (int h = 0; h < 2; ++h) {
            int d = 2*dd + h;
            float s = sb2[d];
            #pragma unroll
            for (int j = 0; j < 32; ++j) s += h1[j] * sW2[d*32+j];
            m2[h] = xs[d] * s * ds;
        }
        ob[dd] = bf16rn(m2[0]) | (bf16rn(m2[1]) << 16);
    }
    uint4* op = (uint4*)(msg + (size_t)e * 16);
    #pragma unroll
    for (int q = 0; q < 4; ++q) {
        uint4 o; o.x=ob[4*q]; o.y=ob[4*q+1]; o.z=ob[4*q+2]; o.w=ob[4*q+3];
        op[q] = o;
    }
}

// One block = (edge-range slice g, node bucket b). Scans its slice's dst,
// ballot-compacts matching edges into an LDS queue, gathers precomputed msg,
// accumulates into padded LDS tile with ds_add, flushes non-atomically.
__global__ __launch_bounds__(256) void bucket_agg_k(
    const int* __restrict__ ei, const unsigned* __restrict__ msg,
    float* __restrict__ staging, int gb, int epb)
{
    __shared__ float lagg[NPB * LSTRIDE];   // 67.6 KB
    __shared__ unsigned queue[CH];          // 8 KB
    __shared__ unsigned qcount;

    int t = threadIdx.x;
    int g = blockIdx.x;        // edge-range slice
    int b = blockIdx.y;        // node bucket

    for (int i = t; i < NPB * LSTRIDE; i += 256) lagg[i] = 0.f;
    int ebase = g * epb;
    int lane = t & 63;
    int passes = epb / CH;

    for (int pass = 0; pass < passes; ++pass) {
        if (t == 0) qcount = 0;
        __syncthreads();
        // ---- scan + compact ----
        #pragma unroll
        for (int i = 0; i < CH / 256; ++i) {
            int loff = pass * CH + i * 256 + t;            // coalesced
            int dst = ei[N_EDGES + ebase + loff];
            bool mine = ((dst >> 9) == b);
            unsigned long long m = __ballot(mine);
            unsigned base = 0;
            if (lane == 0 && m) base = atomicAdd(&qcount, (unsigned)__popcll(m));
            base = (unsigned)__shfl((int)base, 0, 64);
            if (mine) {
                unsigned pos = base + (unsigned)__popcll(m & ((1ull << lane) - 1ull));
                queue[pos] = ((unsigned)loff << 9) | (unsigned)(dst & (NPB - 1));
            }
        }
        __syncthreads();
        unsigned qn = qcount;
        // ---- gather msg + LDS accumulate ----
        for (unsigned qi = t; qi < qn; qi += 256) {
            unsigned pk = queue[qi];
            int loff = (int)(pk >> 9);
            int node = (int)(pk & (NPB - 1));
            size_t e = (size_t)(ebase + loff);
            const uint4* mp = (const uint4*)(msg + e * 16);
            int lb = node * LSTRIDE;
            #pragma unroll
            for (int q = 0; q < 4; ++q) {
                uint4 v = mp[q];
                unsigned w[4] = {v.x, v.y, v.z, v.w};
                #pragma unroll
                for (int c = 0; c < 4; ++c) {
                    float lo = __uint_as_float(w[c] << 16);
                    float hi = __uint_as_float(w[c] & 0xffff0000u);
                    int d = q*8 + c*2;
                    atomicAdd(&lagg[lb + d],     lo);
                    atomicAdd(&lagg[lb + d + 1], hi);
                }
            }
        }
        __syncthreads();
    }
    // ---- non-atomic flush to private staging slot ----
    const size_t sbase = (size_t)(b * gb + g) * (NPB * 32);
    for (int i = t; i < NPB * 32; i += 256) {
        staging[sbase + i] = lagg[(i >> 5) * LSTRIDE + (i & 31)];
    }
}

__global__ __launch_bounds__(256) void ln_colsum_k(
    const float* __restrict__ x, const float* __restrict__ staging,
    const float* __restrict__ rwp, const float* __restrict__ gamma,
    const float* __restrict__ beta, const float* __restrict__ ntypes,
    float* __restrict__ colsum, int gb)
{
    int t = threadIdx.x;
    int n = blockIdx.x * 256 + t;
    int b = n >> 9;              // bucket
    int nn = n & (NPB - 1);
    float acc[32];
    #pragma unroll
    for (int d = 0; d < 32; ++d) acc[d] = 0.f;
    for (int g = 0; g < gb; ++g) {   // fold the staging reduce (coalesced)
        const float4* sp = (const float4*)(staging
            + (size_t)(b * gb + g) * (NPB * 32) + (size_t)nn * 32);
        #pragma unroll
        for (int i = 0; i < 8; ++i) {
            float4 v = sp[i];
            acc[4*i+0]+=v.x; acc[4*i+1]+=v.y; acc[4*i+2]+=v.z; acc[4*i+3]+=v.w;
        }
    }
    float r = rwp[0];
    const float4* xp = (const float4*)(x + (size_t)n * 32);
    float h[32];
    float mu = 0.f;
    #pragma unroll
    for (int i = 0; i < 8; ++i) {
        float4 xv = xp[i];
        h[4*i+0] = xv.x + acc[4*i+0] * r;
        h[4*i+1] = xv.y + acc[4*i+1] * r;
        h[4*i+2] = xv.z + acc[4*i+2] * r;
        h[4*i+3] = xv.w + acc[4*i+3] * r;
        mu += h[4*i+0] + h[4*i+1] + h[4*i+2] + h[4*i+3];
    }
    mu *= (1.f/32.f);
    float var = 0.f;
    #pragma unroll
    for (int d = 0; d < 32; ++d) { float dl = h[d]-mu; var += dl*dl; }
    var *= (1.f/32.f);
    float inv = 1.f / sqrtf(var + 1e-5f);

    int lane = t & 63;
    float keep = 0.f;
    #pragma unroll
    for (int d = 0; d < 32; ++d) {
        float s = (h[d]-mu) * inv * gamma[d] + beta[d];
        #pragma unroll
        for (int off = 1; off < 64; off <<= 1) s += __shfl_xor(s, off, 64);
        if (lane == d) keep = s;
    }
    float nts = ntypes[n];
    #pragma unroll
    for (int off = 1; off < 64; off <<= 1) nts += __shfl_xor(nts, off, 64);

    if (lane < 32) unsafeAtomicAdd(&colsum[lane], keep);
    if (lane == 32) unsafeAtomicAdd(&colsum[32], nts);
}

__global__ void fill_k(const float* __restrict__ colsum, float* __restrict__ out)
{
    __shared__ float s_nx[32];
    __shared__ float s_nt;
    if (threadIdx.x < 32) s_nx[threadIdx.x] = colsum[threadIdx.x] * (1.f/4096.f);
    if (threadIdx.x == 0) s_nt = colsum[32] * (1.f/4096.f);
    __syncthreads();
    const unsigned T4 = 43651072u / 4u;
    unsigned i = blockIdx.x * blockDim.x + threadIdx.x;
    unsigned stride = gridDim.x * blockDim.x;
    float4* o = (float4*)out;
    const float AV = 1.f/4096.f;   // exact: softmax of k identical logits
    for (unsigned v = i; v < T4; v += stride) {
        unsigned f = v * 4u;
        float4 val;
        if (f < 131072u) {                      // new_x: colsum(h)/4096 broadcast
            unsigned c = f & 31u;
            val.x = s_nx[c]; val.y = s_nx[c+1]; val.z = s_nx[c+2]; val.w = s_nx[c+3];
        } else if (f < 9568256u) {              // new_edge_index + new_edge_attr: 0
            val.x = val.y = val.z = val.w = 0.f;
        } else if (f < 43122688u) {             // A: uniform 1/4096
            val.x = val.y = val.z = val.w = AV;
        } else if (f < 43126784u) {             // new_node_types
            val.x = val.y = val.z = val.w = s_nt;
        } else {                                // edge_mask: all false
            val.x = val.y = val.z = val.w = 0.f;
        }
        o[v] = val;
    }
}

extern "C" void kernel_launch(void* const* d_in, const int* in_sizes, int n_in,
                              void* d_out, int out_size, void* d_ws, size_t ws_size,
                              hipStream_t stream) {
    const float* x     = (const float*)d_in[0];
    const int*   ei    = (const int*)  d_in[1];
    const float* ea    = (const float*)d_in[2];
    const float* ntyp  = (const float*)d_in[3];
    const float* We1   = (const float*)d_in[4];
    const float* be1   = (const float*)d_in[5];
    const float* We2   = (const float*)d_in[6];
    const float* be2   = (const float*)d_in[7];
    const float* Wn1   = (const float*)d_in[8];
    const float* bn1   = (const float*)d_in[9];
    const float* Wn2   = (const float*)d_in[10];
    const float* bn2   = (const float*)d_in[11];
    const float* rw    = (const float*)d_in[12];
    const float* dsc   = (const float*)d_in[13];
    const float* gamma = (const float*)d_in[14];
    const float* beta  = (const float*)d_in[15];

    char* ws = (char*)d_ws;
    float*    xt      = (float*)(ws);
    float*    colsum  = (float*)(ws + (1u<<20));
    unsigned* msg     = (unsigned*)(ws + (2u<<20));
    float*    staging = (float*)(ws + (34u<<20));
    float*    out     = (float*)d_out;

    // adaptive slice count: layout needs 34 MiB + gb MiB
    int gb = 32;
    while (gb > 1 && (size_t)(34u<<20) + (size_t)gb * (1u<<20) > ws_size) gb >>= 1;
    int epb = N_EDGES / gb;

    hipMemsetAsync(colsum, 0, 256, stream);

    node_transform_k<<<N_NODES/256, 256, 0, stream>>>(x, Wn1, bn1, Wn2, bn2, xt);
    edge_msg_k<<<N_EDGES/256, 256, 0, stream>>>(ea, ei, We1, be1, We2, be2, xt, dsc, msg);
    bucket_agg_k<<<dim3(gb, NB), 256, 0, stream>>>(ei, msg, staging, gb, epb);
    ln_colsum_k<<<N_NODES/256, 256, 0, stream>>>(x, staging, rw, gamma, beta, ntyp,
                                                 colsum, gb);
    fill_k<<<4096, 256, 0, stream>>>(colsum, out);
}